// Round 4
// baseline (237.982 us; speedup 1.0000x reference)
//
#include <hip/hip_runtime.h>
#include <cstdint>

#define LRELU_ALPHA 0.2f
#define NEG_INF -9000000000000000.0f
#define L2E 1.4426950408889634f

typedef __bf16 bf16x8 __attribute__((ext_vector_type(8)));
typedef float floatx4 __attribute__((ext_vector_type(4)));

constexpr int Bb = 8, Nn = 2048, Ff = 64;
constexpr int TJ = 64;                  // j-tile width
constexpr int SEG = 8;                  // j-segments (flash partial-softmax split)
constexpr int SEGJ = Nn / SEG;          // 256 j-cols per segment
constexpr int SEGT = SEGJ / TJ;         // 4 j-tiles per segment
constexpr int NROWS = Bb * Nn;          // 16384 global rows
constexpr int LSTR = 264;               // LDS row stride in bf16: 528 B = 33*16 -> group-cycling b128

__device__ __forceinline__ unsigned f2bf_u(float f) {
    unsigned u = __builtin_bit_cast(unsigned, f);
    return u + 0x7FFFu + ((u >> 16) & 1u);   // round-to-nearest-even, result in high 16
}

__device__ __forceinline__ unsigned short f2bf(float f) {
    return (unsigned short)(f2bf_u(f) >> 16);
}

__device__ __forceinline__ unsigned pkbf(float lo, float hi) {
    return (f2bf_u(lo) >> 16) | (f2bf_u(hi) & 0xFFFF0000u);
}

// ---------------- Kernel 1: h = x@W (fp32); s1 = (h.a1)*log2e, s2 = (h.a2)*log2e; hT bf16 ----
// grid 512, block 256 = 4 waves; wave w owns rows il = w*8 + r. lane = output feature.
__global__ __launch_bounds__(256) void gat_prep(
    const float* __restrict__ x, const float* __restrict__ W, const float* __restrict__ a,
    unsigned short* __restrict__ hT, float* __restrict__ s1g, float* __restrict__ s2g)
{
    constexpr int STR2 = 36;                    // [f][il] stride (bank-stride 18 -> 2-way = free)
    __shared__ unsigned short hblk[64 * STR2];
    const int tid = threadIdx.x;
    const int blk = blockIdx.x;                 // 512 blocks: 64 row-blocks x 8 batches
    const int b  = blk >> 6;
    const int i0 = (blk & 63) * 32;
    const int w    = tid >> 6;
    const int lane = tid & 63;                  // lane = output feature f

    float wcol[64];
    #pragma unroll
    for (int k = 0; k < 64; ++k) wcol[k] = W[k * 64 + lane];
    const float a1 = a[lane], a2 = a[64 + lane];

    for (int r = 0; r < 8; ++r) {
        const int il = w * 8 + r;
        const int i  = i0 + il;
        const float* xrow = x + ((size_t)(b * Nn + i)) * 64;   // wave-uniform -> s_loads
        float h = 0.f;
        #pragma unroll
        for (int k = 0; k < 64; ++k) h = fmaf(xrow[k], wcol[k], h);
        float p1 = h * a1, p2 = h * a2;
        #pragma unroll
        for (int off = 32; off; off >>= 1) {
            p1 += __shfl_xor(p1, off);
            p2 += __shfl_xor(p2, off);
        }
        // fold log2(e) into the scores: lrelu(x)*c == lrelu(x*c) for c>0, so softmax can
        // use exp2 directly downstream.
        if (lane == 0) { s1g[b * Nn + i] = p1 * L2E; s2g[b * Nn + i] = p2 * L2E; }
        hblk[lane * STR2 + il] = f2bf(h);          // transpose via LDS
    }
    __syncthreads();
    {
        const int f = tid >> 2, c = (tid & 3) * 8;
        uint4 v = *reinterpret_cast<const uint4*>(&hblk[f * STR2 + c]);
        *reinterpret_cast<uint4*>(hT + ((size_t)b * 64 + f) * Nn + i0 + c) = v;
    }
}

// ---------------- Kernel 2: fused masked-softmax attention + PV (flash, barrier-free loop) ---
// Block = 256 threads (4 waves), 64 rows/block, one j-segment (256 cols).
// hT segment slice (32 KB) staged to LDS ONCE; K-loop has NO barriers — adj reads are
// register-double-buffered 2 tiles deep so the compiler emits fine-grained vmcnt waits.
// e-compute lane mapping == MFMA A-fragment layout: m = lane&15, k = (lane>>4)*8 + jj.
__global__ __launch_bounds__(256, 4) void gat_attn(
    const int* __restrict__ adj, const unsigned short* __restrict__ hT,
    const float* __restrict__ s1g, const float* __restrict__ s2g,
    float* __restrict__ m_part, float* __restrict__ l_part, float* __restrict__ O_part)
{
    __shared__ unsigned short hT_lds[64 * LSTR];   // [f][j_local] bf16, 33792 B
    __shared__ float s2_lds[SEGJ];                 // 1 KB

    const int tid  = threadIdx.x;
    const int blk  = blockIdx.x;          // 2048 blocks, seg-major
    const int seg  = blk >> 8;
    const int grp  = blk & 255;
    const int gr0  = grp * 64;
    const int b    = gr0 >> 11;
    const int i0   = gr0 & 2047;
    const int w    = tid >> 6;
    const int lane = tid & 63;
    const int fl   = lane & 15;           // A-row (i) in e-phase; B-col (f) in mfma phase
    const int q    = lane >> 4;           // quad id: k-group selector

    const int i = i0 + w * 16 + fl;       // this lane's score row
    const float s1v = s1g[b * Nn + i];
    const int* adj_row = adj + ((size_t)(b * Nn + i)) * Nn;
    const unsigned short* hTb = hT + (size_t)b * 64 * Nn;
    const int jseg0 = seg * SEGJ;

    float m = NEG_INF, l = 0.f;
    floatx4 C[4] = {};                    // 4 f-tiles of 16x16 C

    // ---- adj prefetch helper: 16 ints covering one 64-col tile for this lane's row ----
    auto loadAdj = [&](int4* dst, int jcol0) {
        const int* p0 = adj_row + jcol0 + q * 8;
        dst[0] = *reinterpret_cast<const int4*>(p0);
        dst[1] = *reinterpret_cast<const int4*>(p0 + 4);
        const int* p1 = adj_row + jcol0 + 32 + q * 8;
        dst[2] = *reinterpret_cast<const int4*>(p1);
        dst[3] = *reinterpret_cast<const int4*>(p1 + 4);
    };

    int4 bufA[4], bufB[4];
    loadAdj(bufA, jseg0);                 // in flight during LDS staging
    loadAdj(bufB, jseg0 + TJ);

    // ---- stage hT segment slice [64 f][256 j] + s2 slice to LDS (once) ----
    {
        const int fr = tid >> 2;
        const int c0 = (tid & 3) * 64;
        const unsigned short* gsrc = hTb + (size_t)fr * Nn + jseg0 + c0;
        #pragma unroll
        for (int k = 0; k < 8; ++k) {
            uint4 v = reinterpret_cast<const uint4*>(gsrc)[k];
            reinterpret_cast<uint4*>(&hT_lds[fr * LSTR + c0])[k] = v;
        }
        s2_lds[tid] = s2g[b * Nn + jseg0 + tid];
    }
    __syncthreads();                      // the ONLY barrier

    // ---- one 64-col tile: scores -> online softmax -> P(bf16) -> MFMA accumulate ----
    auto tile_body = [&](const int4* av4, int tloc) {
        const int* av = reinterpret_cast<const int*>(av4);
        float e[16];
        #pragma unroll
        for (int t = 0; t < 2; ++t) {
            float s2v[8];
            *reinterpret_cast<float4*>(&s2v[0]) =
                *reinterpret_cast<const float4*>(&s2_lds[tloc * 64 + t * 32 + q * 8]);
            *reinterpret_cast<float4*>(&s2v[4]) =
                *reinterpret_cast<const float4*>(&s2_lds[tloc * 64 + t * 32 + q * 8 + 4]);
            #pragma unroll
            for (int jj = 0; jj < 8; ++jj) {
                float ev = s1v + s2v[jj];
                ev = fmaxf(ev, LRELU_ALPHA * ev);              // leaky_relu (log2-scaled)
                e[t * 8 + jj] = (av[t * 8 + jj] > 0) ? ev : NEG_INF;
            }
        }
        float tmax = e[0];
        #pragma unroll
        for (int k = 1; k < 16; ++k) tmax = fmaxf(tmax, e[k]);
        tmax = fmaxf(tmax, __shfl_xor(tmax, 16));
        tmax = fmaxf(tmax, __shfl_xor(tmax, 32));
        const float m_new = fmaxf(m, tmax);
        const float alpha_s = exp2f(m - m_new);
        m = m_new;

        float tsum = 0.f, p[16];
        #pragma unroll
        for (int k = 0; k < 16; ++k) {
            p[k] = exp2f(e[k] - m_new);
            tsum += p[k];
        }
        tsum += __shfl_xor(tsum, 16);
        tsum += __shfl_xor(tsum, 32);
        l = l * alpha_s + tsum;

        uint4 pl0, pl1;                   // packed bf16 A-fragments (A-layout already)
        pl0.x = pkbf(p[0], p[1]);  pl0.y = pkbf(p[2], p[3]);
        pl0.z = pkbf(p[4], p[5]);  pl0.w = pkbf(p[6], p[7]);
        pl1.x = pkbf(p[8], p[9]);  pl1.y = pkbf(p[10], p[11]);
        pl1.z = pkbf(p[12], p[13]); pl1.w = pkbf(p[14], p[15]);
        const bf16x8 A0 = __builtin_bit_cast(bf16x8, pl0);
        const bf16x8 A1 = __builtin_bit_cast(bf16x8, pl1);

        float ac[4];
        #pragma unroll
        for (int r = 0; r < 4; ++r) ac[r] = __shfl(alpha_s, q * 4 + r);
        #pragma unroll
        for (int u = 0; u < 4; ++u)
            #pragma unroll
            for (int r = 0; r < 4; ++r) C[u][r] *= ac[r];

        #pragma unroll
        for (int u = 0; u < 4; ++u) {
            const bf16x8 B0 = *reinterpret_cast<const bf16x8*>(
                &hT_lds[(u * 16 + fl) * LSTR + tloc * 64 + q * 8]);
            C[u] = __builtin_amdgcn_mfma_f32_16x16x32_bf16(A0, B0, C[u], 0, 0, 0);
            const bf16x8 B1 = *reinterpret_cast<const bf16x8*>(
                &hT_lds[(u * 16 + fl) * LSTR + tloc * 64 + 32 + q * 8]);
            C[u] = __builtin_amdgcn_mfma_f32_16x16x32_bf16(A1, B1, C[u], 0, 0, 0);
        }
    };

    // barrier-free, software-pipelined K-loop (SEGT = 4, unrolled)
    tile_body(bufA, 0);
    loadAdj(bufA, jseg0 + 2 * TJ);
    tile_body(bufB, 1);
    loadAdj(bufB, jseg0 + 3 * TJ);
    tile_body(bufA, 2);
    tile_body(bufB, 3);

    // epilogue: store partial m, l, unnormalized O for this segment
    if (q == 0) {
        const int ri = b * Nn + i;
        m_part[seg * NROWS + ri] = m;
        l_part[seg * NROWS + ri] = l;
    }
    #pragma unroll
    for (int u = 0; u < 4; ++u) {
        #pragma unroll
        for (int r = 0; r < 4; ++r) {
            const int orow = i0 + w * 16 + q * 4 + r;
            O_part[((size_t)seg * NROWS + b * Nn + orow) * 64 + u * 16 + fl] = C[u][r];
        }
    }
}

// ---------------- Kernel 3: merge segment partials, normalize, ELU ------------------------
__global__ __launch_bounds__(256) void gat_merge(
    const float* __restrict__ m_part, const float* __restrict__ l_part,
    const float* __restrict__ O_part, float* __restrict__ out)
{
    const int tid = threadIdx.x;
    const int ri  = blockIdx.x * 4 + (tid >> 6);   // global row
    const int f   = tid & 63;

    float mv[SEG];
    #pragma unroll
    for (int s = 0; s < SEG; ++s) mv[s] = m_part[s * NROWS + ri];
    float mstar = mv[0];
    #pragma unroll
    for (int s = 1; s < SEG; ++s) mstar = fmaxf(mstar, mv[s]);

    float lsum = 0.f, acc = 0.f;
    #pragma unroll
    for (int s = 0; s < SEG; ++s) {
        const float wgt = exp2f(mv[s] - mstar);    // m already log2-scaled
        lsum += l_part[s * NROWS + ri] * wgt;
        acc  += O_part[((size_t)s * NROWS + ri) * 64 + f] * wgt;
    }
    float v = acc / lsum;
    v = (v > 0.f) ? v : (exp2f(v * L2E) - 1.f);    // elu, alpha=1
    out[(size_t)ri * 64 + f] = v;
}

extern "C" void kernel_launch(void* const* d_in, const int* in_sizes, int n_in,
                              void* d_out, int out_size, void* d_ws, size_t ws_size,
                              hipStream_t stream) {
    const float* x   = (const float*)d_in[0];
    const int*   adj = (const int*)d_in[1];
    const float* W   = (const float*)d_in[2];
    const float* a   = (const float*)d_in[3];
    float* out = (float*)d_out;

    char* p = (char*)d_ws;
    unsigned short* hT = (unsigned short*)p;  p += (size_t)Bb * 64 * Nn * sizeof(unsigned short);
    float* s1 = (float*)p;                    p += (size_t)NROWS * sizeof(float);
    float* s2 = (float*)p;                    p += (size_t)NROWS * sizeof(float);
    float* m_part = (float*)p;                p += (size_t)SEG * NROWS * sizeof(float);
    float* l_part = (float*)p;                p += (size_t)SEG * NROWS * sizeof(float);
    float* O_part = (float*)p;

    gat_prep<<<dim3(Bb * Nn / 32), dim3(256), 0, stream>>>(x, W, a, hT, s1, s2);
    gat_attn<<<dim3(SEG * (Bb * Nn / 64)), dim3(256), 0, stream>>>(
        adj, hT, s1, s2, m_part, l_part, O_part);
    gat_merge<<<dim3(NROWS / 4), dim3(256), 0, stream>>>(m_part, l_part, O_part, out);
}